// Round 11
// baseline (174.742 us; speedup 1.0000x reference)
//
#include <hip/hip_runtime.h>

typedef __bf16 bf16x8 __attribute__((ext_vector_type(8)));
typedef float f32x4 __attribute__((ext_vector_type(4)));

// mask position tables: (i,j) offsets within 5x5, and flattened s=i*5+j (for W5 gather)
__constant__ int SL_I[3][9] = {{1,1,1,2,2,2,3,3,3},{0,0,2,4,4,0,0,0,0},{0,0,1,1,2,3,3,4,4}};
__constant__ int SL_J[3][9] = {{1,2,3,1,2,3,1,2,3},{0,4,2,0,4,0,0,0,0},{1,3,0,4,2,0,4,1,3}};
__constant__ int SL_S[3][9] = {{6,7,8,11,12,13,16,17,18},{0,4,12,20,24,0,0,0,0},{1,3,5,9,12,15,19,21,23}};

#define GLDS16(gsrc, ldst)                                                        \
  __builtin_amdgcn_global_load_lds(                                               \
      (const __attribute__((address_space(1))) unsigned int*)(gsrc),              \
      (__attribute__((address_space(3))) unsigned int*)(ldst), 16, 0, 0)

static __device__ __forceinline__ unsigned short f2b(float f) {
  return __builtin_bit_cast(unsigned short, (__bf16)f);   // native cvt, RNE
}
static __device__ __forceinline__ float b2f(unsigned short u) {
  unsigned int b = ((unsigned int)u) << 16;
  return __builtin_bit_cast(float, b);
}
// mish(x) = x*tanh(softplus(x)) = x*w/(w+2), w = u*(u+2), u = e^x  (exact identity)
static __device__ __forceinline__ float mish_f(float x) {
  float u = __expf(x);
  float w = u * (u + 2.0f);
  float r = x * w * __builtin_amdgcn_rcpf(w + 2.0f);
  return (x > 20.0f) ? x : r;
}
// swizzle within a 64-col chunk: group (c>>3) ^= (row&7). Involution.
static __device__ __forceinline__ int swz8(int c, int r) {
  return ((((c >> 3) ^ (r & 7)) << 3) | (c & 7));
}
// general 256-wide row offset with per-64-chunk swizzle
static __device__ __forceinline__ int swoff(int c, int r) {
  return (c & ~63) | ((c & 63) ^ ((r & 7) << 3));
}

// ---- prep: X [4096][64][49] f32 -> Xb [49][4096][64] bf16, pre-swizzled ----
__global__ __launch_bounds__(256) void prep_x_k(const float* __restrict__ X,
                                                unsigned short* __restrict__ Xb) {
  __shared__ float tile[3136];
  const int b = blockIdx.x;
  const float* xp = X + (size_t)b * 3136;
  for (int i = threadIdx.x; i < 3136; i += 256) tile[i] = xp[i];
  __syncthreads();
  for (int i = threadIdx.x; i < 3136; i += 256) {
    int s = i >> 6, c = i & 63;
    Xb[(size_t)s * 262144 + (size_t)b * 64 + swz8(c, b)] = f2b(tile[c * 49 + s]);
  }
}

// ---- prep: W5 masked+compressed -> bf16 [27][256][576] (kc = u*64+c), pre-swizzled ----
__global__ __launch_bounds__(256) void prep_w5_k(const float* __restrict__ W5,
                                                 unsigned short* __restrict__ W5c) {
  int idx = blockIdx.x * 256 + threadIdx.x;      // output position; 27*256*9*64
  if (idx >= 27 * 256 * 9 * 64) return;
  int c = idx & 63;
  int t2 = idx >> 6;
  int u = t2 % 9;
  int gm = t2 / 9;                               // gp*256 + m
  int m = gm & 255;
  int g = (gm >> 8) / 9;
  int nm = (g == 1) ? 5 : 9;
  if (u >= nm) return;
  int c_src = swz8(c, m);
  W5c[idx] = f2b(W5[(size_t)gm * 1600 + c_src * 25 + SL_S[g][u]]);
}

__global__ __launch_bounds__(256) void prep_w12_k(const float* __restrict__ W1, const float* __restrict__ W2,
                                                  unsigned short* __restrict__ W1b, unsigned short* __restrict__ W2b) {
  int idx = blockIdx.x * 256 + threadIdx.x;      // 27*256*256
  if (idx < 27 * 256 * 256) {
    int n = (idx >> 8) & 255;
    int c = idx & 63;
    int src = (idx & ~63) | swz8(c, n);
    W1b[idx] = f2b(W1[src]);
    W2b[idx] = f2b(W2[src]);
  }
}

__global__ __launch_bounds__(256) void prep_bn_k(const float* __restrict__ b5, const float* __restrict__ gamma,
                                                 const float* __restrict__ beta, const float* __restrict__ rmean,
                                                 const float* __restrict__ rvar,
                                                 float* __restrict__ bn_a, float* __restrict__ bn_c) {
  int i = blockIdx.x * 256 + threadIdx.x;        // 27*256
  if (i < 27 * 256) {
    float a = gamma[i] * rsqrtf(rvar[i] + 1e-5f);
    bn_a[i] = a;
    bn_c[i] = (b5[i] - rmean[i]) * a + beta[i];
  }
}

// ---- stage 1: z = Xb x W5c^T, BN + mish -> H bf16 [27][4096][256] (H pre-swizzled) ----
// 512 threads / 8 waves; wave = 64x32 sub-tile. 2-phase dbuf, one __syncthreads per K-step.
__global__ __launch_bounds__(512) void gemm1_k(const unsigned short* __restrict__ Xb,
                                               const unsigned short* __restrict__ W5c,
                                               const float* __restrict__ bn_a, const float* __restrict__ bn_c,
                                               unsigned short* __restrict__ H) {
  __shared__ unsigned short smem[32768];  // 2 x (lA 8192 + lB 8192) = 64 KB
  const int t = threadIdx.x;
  const int lane = t & 63;
  const int w = t >> 6;                    // 0..7
  const int wm = w >> 2, wn = w & 3;       // 2 x 4 waves over 128x128
  const int l15 = lane & 15, l4 = lane >> 4;
  const int sw = l15 & 7;
  const int m0 = blockIdx.x * 128, n0 = blockIdx.y * 128;
  const int gp = blockIdx.z;
  const int g = gp / 9, p = gp - g * 9;
  const int pk = p / 3, pv = p - pk * 3;
  const int nm = (g == 1) ? 5 : 9;

  const f32x4 zero = {0.f, 0.f, 0.f, 0.f};
  f32x4 acc[4][2];
#pragma unroll
  for (int i = 0; i < 4; ++i)
#pragma unroll
    for (int j = 0; j < 2; ++j) acc[i][j] = zero;

  auto STAGE = [&](int pbuf, int u) {
    const int s = (pk + SL_I[g][u]) * 7 + (pv + SL_J[g][u]);
    const unsigned short* srcA = Xb + (size_t)s * 262144 + (size_t)m0 * 64;
    unsigned short* dA = smem + pbuf * 16384;
    unsigned short* dB = dA + 8192;
#pragma unroll
    for (int it = 0; it < 2; ++it) {
      int idx = it * 512 + t;
      GLDS16(srcA + idx * 8, dA + idx * 8);
    }
#pragma unroll
    for (int it = 0; it < 2; ++it) {
      int idx = it * 512 + t;
      int row = idx >> 3, ch = idx & 7;
      GLDS16(W5c + (size_t)(gp * 256 + n0 + row) * 576 + u * 64 + ch * 8, dB + idx * 8);
    }
  };

  STAGE(0, 0);
  __syncthreads();
  int cur = 0;
  for (int u = 0; u < nm; ++u) {
    if (u + 1 < nm) STAGE(cur ^ 1, u + 1);    // loads fly during MFMA below
    const unsigned short* lA = smem + cur * 16384;
    const unsigned short* lB = lA + 8192;
#pragma unroll
    for (int kk = 0; kk < 2; ++kk) {
      bf16x8 af[4], bfr[2];
#pragma unroll
      for (int f4 = 0; f4 < 4; ++f4)
        af[f4] = *reinterpret_cast<const bf16x8*>(lA + (wm * 64 + f4 * 16 + l15) * 64 + (((kk * 4 + l4) ^ sw) << 3));
#pragma unroll
      for (int f2 = 0; f2 < 2; ++f2)
        bfr[f2] = *reinterpret_cast<const bf16x8*>(lB + (wn * 32 + f2 * 16 + l15) * 64 + (((kk * 4 + l4) ^ sw) << 3));
#pragma unroll
      for (int i = 0; i < 4; ++i)
#pragma unroll
        for (int j = 0; j < 2; ++j)
          acc[i][j] = __builtin_amdgcn_mfma_f32_16x16x32_bf16(af[i], bfr[j], acc[i][j], 0, 0, 0);
    }
    __syncthreads();   // drains next-tile loads (after MFMA) + barrier
    cur ^= 1;
  }
  // epilogue: BN + mish -> bf16, LDS transpose -> dwordx4 stores (H stored pre-swizzled)
#pragma unroll
  for (int j = 0; j < 2; ++j) {
    const int col = wn * 32 + j * 16 + l15;
    const float a  = bn_a[gp * 256 + n0 + col];
    const float cc = bn_c[gp * 256 + n0 + col];
#pragma unroll
    for (int i = 0; i < 4; ++i) {
      const int r0 = wm * 64 + i * 16 + l4 * 4;
#pragma unroll
      for (int e = 0; e < 4; ++e) {
        const int r = r0 + e;
        float z = acc[i][j][e] * a + cc;
        smem[r * 128 + (col ^ ((r & 7) << 3))] = f2b(mish_f(z));
      }
    }
  }
  __syncthreads();
  {
    unsigned short* Hg = H + (size_t)gp * 1048576;
#pragma unroll
    for (int it = 0; it < 4; ++it) {
      int idx = it * 512 + t;
      int row = idx >> 4, seg = idx & 15;
      int c8 = (seg * 8) ^ ((row & 7) << 3);
      uint4 v = *(const uint4*)(smem + row * 128 + c8);
      int colout = n0 + (seg >> 3) * 64 + (((seg & 7) ^ (row & 7)) << 3);  // pre-swizzled store
      *(uint4*)(Hg + (size_t)(m0 + row) * 256 + colout) = v;
    }
  }
}

// ---- fused stages 2+3: h1 = mish(H x W1^T + b1) kept in LDS; o = h1 x W2^T + b2 -> Obuf ----
// block = (m0, gp); 512 threads / 8 waves (2x4 over 128x256); 128 KB dynamic LDS:
//   h1    : shorts [0, 32768)        (128 x 256 bf16, swizzled)
//   stA   : shorts [32768, 49152)    (2 x 128x64 dbuf for H tiles)
//   stB   : shorts [49152, 65536)    (256x64 single buffer for W1/W2 tiles)
//   (stA+stB region reused as 128x256 transpose buffer in the final epilogue)
__global__ __launch_bounds__(512) void gemm23f_k(const unsigned short* __restrict__ Hb,
                                                 const unsigned short* __restrict__ W1b,
                                                 const unsigned short* __restrict__ W2b,
                                                 const float* __restrict__ b1, const float* __restrict__ b2,
                                                 unsigned short* __restrict__ Obuf) {
  extern __shared__ unsigned short smem[];
  unsigned short* h1  = smem;
  unsigned short* stA = smem + 32768;
  unsigned short* stB = smem + 49152;
  const int t = threadIdx.x;
  const int lane = t & 63;
  const int w = t >> 6;
  const int wm = w >> 2, wn = w & 3;       // wave tile 64 x 64 over 128 x 256
  const int l15 = lane & 15, l4 = lane >> 4;
  const int sw = l15 & 7;
  const int m0 = blockIdx.x * 128;
  const int gp = blockIdx.y;

  const f32x4 zero = {0.f, 0.f, 0.f, 0.f};
  f32x4 acc[4][4];
#pragma unroll
  for (int i = 0; i < 4; ++i)
#pragma unroll
    for (int j = 0; j < 4; ++j) acc[i][j] = zero;

  auto STAGE_A = [&](int pbuf, int kt) {
    unsigned short* dA = stA + pbuf * 8192;
#pragma unroll
    for (int it = 0; it < 2; ++it) {
      int idx = it * 512 + t;
      GLDS16(Hb + (size_t)(gp * 4096 + m0 + (idx >> 3)) * 256 + kt * 64 + (idx & 7) * 8, dA + idx * 8);
    }
  };
  auto STAGE_B = [&](const unsigned short* W, int kt) {
#pragma unroll
    for (int it = 0; it < 4; ++it) {
      int idx = it * 512 + t;
      GLDS16(W + (size_t)(gp * 256 + (idx >> 3)) * 256 + kt * 64 + (idx & 7) * 8, stB + idx * 8);
    }
  };

  // ---- phase 1: h1 = mish(H x W1^T + b1) ----
  STAGE_A(0, 0);
  STAGE_B(W1b, 0);
  __syncthreads();
  int cur = 0;
  for (int kt = 0; kt < 4; ++kt) {
    if (kt < 3) STAGE_A(cur ^ 1, kt + 1);   // A(next) flies under MFMA
    const unsigned short* lA = stA + cur * 8192;
#pragma unroll
    for (int kk = 0; kk < 2; ++kk) {
      bf16x8 af[4], bfr[4];
#pragma unroll
      for (int f4 = 0; f4 < 4; ++f4)
        af[f4] = *reinterpret_cast<const bf16x8*>(lA + (wm * 64 + f4 * 16 + l15) * 64 + (((kk * 4 + l4) ^ sw) << 3));
#pragma unroll
      for (int f4 = 0; f4 < 4; ++f4)
        bfr[f4] = *reinterpret_cast<const bf16x8*>(stB + (wn * 64 + f4 * 16 + l15) * 64 + (((kk * 4 + l4) ^ sw) << 3));
#pragma unroll
      for (int i = 0; i < 4; ++i)
#pragma unroll
        for (int j = 0; j < 4; ++j)
          acc[i][j] = __builtin_amdgcn_mfma_f32_16x16x32_bf16(af[i], bfr[j], acc[i][j], 0, 0, 0);
    }
    __syncthreads();                         // stB readers done; A(next) drained
    if (kt < 3) {
      STAGE_B(W1b, kt + 1);
      __syncthreads();                       // B(next) ready
    }
    cur ^= 1;
  }
  // h1 = mish(acc + b1) -> LDS (swizzled per 64-chunk)
#pragma unroll
  for (int j = 0; j < 4; ++j) {
    const int c = wn * 64 + j * 16 + l15;
    const float bi = b1[gp * 256 + c];
#pragma unroll
    for (int i = 0; i < 4; ++i) {
      const int r0 = wm * 64 + i * 16 + l4 * 4;
#pragma unroll
      for (int e = 0; e < 4; ++e) {
        const int r = r0 + e;
        h1[r * 256 + swoff(c, r)] = f2b(mish_f(acc[i][j][e] + bi));
      }
    }
  }
  __syncthreads();

  // ---- phase 2: o = h1 x W2^T + b2 ----
#pragma unroll
  for (int i = 0; i < 4; ++i)
#pragma unroll
    for (int j = 0; j < 4; ++j) acc[i][j] = zero;
  for (int kt = 0; kt < 4; ++kt) {
    STAGE_B(W2b, kt);
    __syncthreads();                         // W2 tile ready
#pragma unroll
    for (int kk = 0; kk < 2; ++kk) {
      bf16x8 af[4], bfr[4];
#pragma unroll
      for (int f4 = 0; f4 < 4; ++f4)
        af[f4] = *reinterpret_cast<const bf16x8*>(
            h1 + (wm * 64 + f4 * 16 + l15) * 256 + kt * 64 + (((kk * 4 + l4) ^ sw) << 3));
#pragma unroll
      for (int f4 = 0; f4 < 4; ++f4)
        bfr[f4] = *reinterpret_cast<const bf16x8*>(stB + (wn * 64 + f4 * 16 + l15) * 64 + (((kk * 4 + l4) ^ sw) << 3));
#pragma unroll
      for (int i = 0; i < 4; ++i)
#pragma unroll
        for (int j = 0; j < 4; ++j)
          acc[i][j] = __builtin_amdgcn_mfma_f32_16x16x32_bf16(af[i], bfr[j], acc[i][j], 0, 0, 0);
    }
    __syncthreads();                         // stB readers done before restage
  }
  // epilogue: o + b2 -> bf16, LDS transpose (reuse stA/stB region) -> linear dwordx4
  unsigned short* tr = stA;                  // [128][256] = 32768 shorts
#pragma unroll
  for (int j = 0; j < 4; ++j) {
    const int c = wn * 64 + j * 16 + l15;
    const float bi = b2[gp * 256 + c];
#pragma unroll
    for (int i = 0; i < 4; ++i) {
      const int r0 = wm * 64 + i * 16 + l4 * 4;
#pragma unroll
      for (int e = 0; e < 4; ++e) {
        const int r = r0 + e;
        tr[r * 256 + swoff(c, r)] = f2b(acc[i][j][e] + bi);
      }
    }
  }
  __syncthreads();
  {
    unsigned short* Og = Obuf + (size_t)gp * 1048576;
#pragma unroll
    for (int it = 0; it < 8; ++it) {
      int idx = it * 512 + t;
      int row = idx >> 5, seg = idx & 31;
      int c8 = swoff(seg * 8, row);
      uint4 v = *(const uint4*)(tr + row * 256 + c8);
      *(uint4*)(Og + (size_t)(m0 + row) * 256 + seg * 8) = v;
    }
  }
}

// ---- final: copy = sum_{gp<9} o, jump = sum_{gp>=9} o, out = copy*jump ----
__global__ __launch_bounds__(256) void final_k(const unsigned short* __restrict__ O, float* __restrict__ out) {
  const size_t base = ((size_t)blockIdx.x * 256 + threadIdx.x) * 8;
  float cs[8], js[8];
#pragma unroll
  for (int e = 0; e < 8; ++e) { cs[e] = 0.f; js[e] = 0.f; }
#pragma unroll
  for (int gp = 0; gp < 27; ++gp) {
    uint4 v = *(const uint4*)(O + (size_t)gp * 1048576 + base);
    const unsigned short* pv = (const unsigned short*)&v;
    if (gp < 9) {
#pragma unroll
      for (int e = 0; e < 8; ++e) cs[e] += b2f(pv[e]);
    } else {
#pragma unroll
      for (int e = 0; e < 8; ++e) js[e] += b2f(pv[e]);
    }
  }
  float4 o0 = {cs[0] * js[0], cs[1] * js[1], cs[2] * js[2], cs[3] * js[3]};
  float4 o1 = {cs[4] * js[4], cs[5] * js[5], cs[6] * js[6], cs[7] * js[7]};
  *(float4*)(out + base) = o0;
  *(float4*)(out + base + 4) = o1;
}

extern "C" void kernel_launch(void* const* d_in, const int* in_sizes, int n_in,
                              void* d_out, int out_size, void* d_ws, size_t ws_size,
                              hipStream_t stream) {
  const float* X     = (const float*)d_in[0];
  const float* W5    = (const float*)d_in[1];
  const float* b5    = (const float*)d_in[2];
  const float* gamma = (const float*)d_in[3];
  const float* beta  = (const float*)d_in[4];
  const float* rmean = (const float*)d_in[5];
  const float* rvar  = (const float*)d_in[6];
  const float* W1    = (const float*)d_in[7];
  const float* b1    = (const float*)d_in[8];
  const float* W2    = (const float*)d_in[9];
  const float* b2    = (const float*)d_in[10];
  float* out = (float*)d_out;
  char* ws = (char*)d_ws;

  // ws layout (bytes), all 16B-aligned
  unsigned short* W5c  = (unsigned short*)(ws);              //  7,962,624
  unsigned short* W1b  = (unsigned short*)(ws + 7962624);    //  3,538,944
  unsigned short* W2b  = (unsigned short*)(ws + 11501568);   //  3,538,944
  float*          bn_a = (float*)(ws + 15040512);            //     27,648
  float*          bn_c = (float*)(ws + 15068160);            //     27,648
  unsigned short* Xb   = (unsigned short*)(ws + 15095808);   // 25,690,112
  unsigned short* Hbuf = (unsigned short*)(ws + 40785920);   // 56,623,104
  unsigned short* Obuf = (unsigned short*)(ws + 97409024);   // 56,623,104 (distinct from Hbuf: fused kernel reads Hbuf while writing Obuf)

  // allow 128 KB dynamic LDS for the fused kernel (host-side, idempotent)
  (void)hipFuncSetAttribute(reinterpret_cast<const void*>(gemm23f_k),
                            hipFuncAttributeMaxDynamicSharedMemorySize, 131072);

  prep_x_k<<<4096, 256, 0, stream>>>(X, Xb);
  prep_w5_k<<<15552, 256, 0, stream>>>(W5, W5c);
  prep_w12_k<<<6912, 256, 0, stream>>>(W1, W2, W1b, W2b);
  prep_bn_k<<<27, 256, 0, stream>>>(b5, gamma, beta, rmean, rvar, bn_a, bn_c);

  gemm1_k<<<dim3(32, 2, 27), 512, 0, stream>>>(Xb, W5c, bn_a, bn_c, Hbuf);
  gemm23f_k<<<dim3(32, 27), 512, 131072, stream>>>(Hbuf, W1b, W2b, b1, b2, Obuf);
  final_k<<<512, 256, 0, stream>>>(Obuf, out);
}

// Round 12
// 161.599 us; speedup vs baseline: 1.0813x; 1.0813x over previous
//
#include <hip/hip_runtime.h>

typedef __bf16 bf16x8 __attribute__((ext_vector_type(8)));
typedef float f32x4 __attribute__((ext_vector_type(4)));

// mask position tables: (i,j) offsets within 5x5, and flattened s=i*5+j (for W5 gather)
__constant__ int SL_I[3][9] = {{1,1,1,2,2,2,3,3,3},{0,0,2,4,4,0,0,0,0},{0,0,1,1,2,3,3,4,4}};
__constant__ int SL_J[3][9] = {{1,2,3,1,2,3,1,2,3},{0,4,2,0,4,0,0,0,0},{1,3,0,4,2,0,4,1,3}};
__constant__ int SL_S[3][9] = {{6,7,8,11,12,13,16,17,18},{0,4,12,20,24,0,0,0,0},{1,3,5,9,12,15,19,21,23}};

#define GLDS16(gsrc, ldst)                                                        \
  __builtin_amdgcn_global_load_lds(                                               \
      (const __attribute__((address_space(1))) unsigned int*)(gsrc),              \
      (__attribute__((address_space(3))) unsigned int*)(ldst), 16, 0, 0)

static __device__ __forceinline__ unsigned short f2b(float f) {
  return __builtin_bit_cast(unsigned short, (__bf16)f);   // native cvt, RNE
}
static __device__ __forceinline__ float b2f(unsigned short u) {
  unsigned int b = ((unsigned int)u) << 16;
  return __builtin_bit_cast(float, b);
}
// mish(x) = x*tanh(softplus(x)) = x*w/(w+2), w = u*(u+2), u = e^x  (exact identity)
static __device__ __forceinline__ float mish_f(float x) {
  float u = __expf(x);
  float w = u * (u + 2.0f);
  float r = x * w * __builtin_amdgcn_rcpf(w + 2.0f);
  return (x > 20.0f) ? x : r;
}
// swizzle within a 64-col chunk: group (c>>3) ^= (row&7). Involution.
static __device__ __forceinline__ int swz8(int c, int r) {
  return ((((c >> 3) ^ (r & 7)) << 3) | (c & 7));
}
// general 256-wide row offset with per-64-chunk swizzle
static __device__ __forceinline__ int swoff(int c, int r) {
  return (c & ~63) | ((c & 63) ^ ((r & 7) << 3));
}

// ---- prep: X [4096][64][49] f32 -> Xb [49][4096][64] bf16, pre-swizzled ----
__global__ __launch_bounds__(256) void prep_x_k(const float* __restrict__ X,
                                                unsigned short* __restrict__ Xb) {
  __shared__ float tile[3136];
  const int b = blockIdx.x;
  const float* xp = X + (size_t)b * 3136;
  for (int i = threadIdx.x; i < 3136; i += 256) tile[i] = xp[i];
  __syncthreads();
  for (int i = threadIdx.x; i < 3136; i += 256) {
    int s = i >> 6, c = i & 63;
    Xb[(size_t)s * 262144 + (size_t)b * 64 + swz8(c, b)] = f2b(tile[c * 49 + s]);
  }
}

// ---- prep: W5 masked+compressed -> bf16 [27][256][576] (kc = u*64+c), pre-swizzled ----
__global__ __launch_bounds__(256) void prep_w5_k(const float* __restrict__ W5,
                                                 unsigned short* __restrict__ W5c) {
  int idx = blockIdx.x * 256 + threadIdx.x;      // output position; 27*256*9*64
  if (idx >= 27 * 256 * 9 * 64) return;
  int c = idx & 63;
  int t2 = idx >> 6;
  int u = t2 % 9;
  int gm = t2 / 9;                               // gp*256 + m
  int m = gm & 255;
  int g = (gm >> 8) / 9;
  int nm = (g == 1) ? 5 : 9;
  if (u >= nm) return;
  int c_src = swz8(c, m);
  W5c[idx] = f2b(W5[(size_t)gm * 1600 + c_src * 25 + SL_S[g][u]]);
}

__global__ __launch_bounds__(256) void prep_w12_k(const float* __restrict__ W1, const float* __restrict__ W2,
                                                  unsigned short* __restrict__ W1b, unsigned short* __restrict__ W2b) {
  int idx = blockIdx.x * 256 + threadIdx.x;      // 27*256*256
  if (idx < 27 * 256 * 256) {
    int n = (idx >> 8) & 255;
    int c = idx & 63;
    int src = (idx & ~63) | swz8(c, n);
    W1b[idx] = f2b(W1[src]);
    W2b[idx] = f2b(W2[src]);
  }
}

__global__ __launch_bounds__(256) void prep_bn_k(const float* __restrict__ b5, const float* __restrict__ gamma,
                                                 const float* __restrict__ beta, const float* __restrict__ rmean,
                                                 const float* __restrict__ rvar,
                                                 float* __restrict__ bn_a, float* __restrict__ bn_c) {
  int i = blockIdx.x * 256 + threadIdx.x;        // 27*256
  if (i < 27 * 256) {
    float a = gamma[i] * rsqrtf(rvar[i] + 1e-5f);
    bn_a[i] = a;
    bn_c[i] = (b5[i] - rmean[i]) * a + beta[i];
  }
}

// ---- stage 1: z = Xb x W5c^T, BN + mish -> H bf16 [27][4096][256] (H pre-swizzled) ----
// 512 threads / 8 waves; wave = 64x32 sub-tile. 2-phase dbuf, one __syncthreads per K-step.
__global__ __launch_bounds__(512) void gemm1_k(const unsigned short* __restrict__ Xb,
                                               const unsigned short* __restrict__ W5c,
                                               const float* __restrict__ bn_a, const float* __restrict__ bn_c,
                                               unsigned short* __restrict__ H) {
  __shared__ unsigned short smem[32768];  // 2 x (lA 8192 + lB 8192) = 64 KB
  const int t = threadIdx.x;
  const int lane = t & 63;
  const int w = t >> 6;                    // 0..7
  const int wm = w >> 2, wn = w & 3;       // 2 x 4 waves over 128x128
  const int l15 = lane & 15, l4 = lane >> 4;
  const int sw = l15 & 7;
  const int m0 = blockIdx.x * 128, n0 = blockIdx.y * 128;
  const int gp = blockIdx.z;
  const int g = gp / 9, p = gp - g * 9;
  const int pk = p / 3, pv = p - pk * 3;
  const int nm = (g == 1) ? 5 : 9;

  const f32x4 zero = {0.f, 0.f, 0.f, 0.f};
  f32x4 acc[4][2];
#pragma unroll
  for (int i = 0; i < 4; ++i)
#pragma unroll
    for (int j = 0; j < 2; ++j) acc[i][j] = zero;

  auto STAGE = [&](int pbuf, int u) {
    const int s = (pk + SL_I[g][u]) * 7 + (pv + SL_J[g][u]);
    const unsigned short* srcA = Xb + (size_t)s * 262144 + (size_t)m0 * 64;
    unsigned short* dA = smem + pbuf * 16384;
    unsigned short* dB = dA + 8192;
#pragma unroll
    for (int it = 0; it < 2; ++it) {
      int idx = it * 512 + t;
      GLDS16(srcA + idx * 8, dA + idx * 8);
    }
#pragma unroll
    for (int it = 0; it < 2; ++it) {
      int idx = it * 512 + t;
      int row = idx >> 3, ch = idx & 7;
      GLDS16(W5c + (size_t)(gp * 256 + n0 + row) * 576 + u * 64 + ch * 8, dB + idx * 8);
    }
  };

  STAGE(0, 0);
  __syncthreads();
  int cur = 0;
  for (int u = 0; u < nm; ++u) {
    if (u + 1 < nm) STAGE(cur ^ 1, u + 1);    // loads fly during MFMA below
    const unsigned short* lA = smem + cur * 16384;
    const unsigned short* lB = lA + 8192;
#pragma unroll
    for (int kk = 0; kk < 2; ++kk) {
      bf16x8 af[4], bfr[2];
#pragma unroll
      for (int f4 = 0; f4 < 4; ++f4)
        af[f4] = *reinterpret_cast<const bf16x8*>(lA + (wm * 64 + f4 * 16 + l15) * 64 + (((kk * 4 + l4) ^ sw) << 3));
#pragma unroll
      for (int f2 = 0; f2 < 2; ++f2)
        bfr[f2] = *reinterpret_cast<const bf16x8*>(lB + (wn * 32 + f2 * 16 + l15) * 64 + (((kk * 4 + l4) ^ sw) << 3));
#pragma unroll
      for (int i = 0; i < 4; ++i)
#pragma unroll
        for (int j = 0; j < 2; ++j)
          acc[i][j] = __builtin_amdgcn_mfma_f32_16x16x32_bf16(af[i], bfr[j], acc[i][j], 0, 0, 0);
    }
    __syncthreads();   // drains next-tile loads (after MFMA) + barrier
    cur ^= 1;
  }
  // epilogue: BN + mish -> bf16, LDS transpose -> dwordx4 stores (H stored pre-swizzled)
#pragma unroll
  for (int j = 0; j < 2; ++j) {
    const int col = wn * 32 + j * 16 + l15;
    const float a  = bn_a[gp * 256 + n0 + col];
    const float cc = bn_c[gp * 256 + n0 + col];
#pragma unroll
    for (int i = 0; i < 4; ++i) {
      const int r0 = wm * 64 + i * 16 + l4 * 4;
#pragma unroll
      for (int e = 0; e < 4; ++e) {
        const int r = r0 + e;
        float z = acc[i][j][e] * a + cc;
        smem[r * 128 + (col ^ ((r & 7) << 3))] = f2b(mish_f(z));
      }
    }
  }
  __syncthreads();
  {
    unsigned short* Hg = H + (size_t)gp * 1048576;
#pragma unroll
    for (int it = 0; it < 4; ++it) {
      int idx = it * 512 + t;
      int row = idx >> 4, seg = idx & 15;
      int c8 = (seg * 8) ^ ((row & 7) << 3);
      uint4 v = *(const uint4*)(smem + row * 128 + c8);
      int colout = n0 + (seg >> 3) * 64 + (((seg & 7) ^ (row & 7)) << 3);  // pre-swizzled store
      *(uint4*)(Hg + (size_t)(m0 + row) * 256 + colout) = v;
    }
  }
}

// ---- fused stages 2+3: h1 = mish(H x W1^T + b1) kept in LDS; o = h1 x W2^T + b2 -> Obuf ----
// block = (m0=64-row tile, gp); 512 threads / 8 waves (2x4 over 64x256); 80 KB dynamic LDS:
//   h1  : shorts [0, 16384)       (64 x 256 bf16, swizzled)
//   stA : shorts [16384, 24576)   (2 x 64x64 dbuf for H tiles)
//   stB : shorts [24576, 40960)   (256x64 single buffer for W1/W2 tiles)
//   (stA+stB region reused as 64x256 transpose buffer in the final epilogue)
__global__ __launch_bounds__(512) void gemm23f_k(const unsigned short* __restrict__ Hb,
                                                 const unsigned short* __restrict__ W1b,
                                                 const unsigned short* __restrict__ W2b,
                                                 const float* __restrict__ b1, const float* __restrict__ b2,
                                                 unsigned short* __restrict__ Obuf) {
  extern __shared__ unsigned short smem[];
  unsigned short* h1  = smem;
  unsigned short* stA = smem + 16384;
  unsigned short* stB = smem + 24576;
  const int t = threadIdx.x;
  const int lane = t & 63;
  const int w = t >> 6;
  const int wm = w >> 2, wn = w & 3;       // wave tile 32 x 64 over 64 x 256
  const int l15 = lane & 15, l4 = lane >> 4;
  const int sw = l15 & 7;
  const int m0 = blockIdx.x * 64;
  const int gp = blockIdx.y;

  const f32x4 zero = {0.f, 0.f, 0.f, 0.f};
  f32x4 acc[2][4];
#pragma unroll
  for (int i = 0; i < 2; ++i)
#pragma unroll
    for (int j = 0; j < 4; ++j) acc[i][j] = zero;

  auto STAGE_A = [&](int pbuf, int kt) {
    unsigned short* dA = stA + pbuf * 4096;
    GLDS16(Hb + (size_t)(gp * 4096 + m0 + (t >> 3)) * 256 + kt * 64 + (t & 7) * 8, dA + t * 8);
  };
  auto STAGE_B = [&](const unsigned short* W, int kt) {
#pragma unroll
    for (int it = 0; it < 4; ++it) {
      int idx = it * 512 + t;
      GLDS16(W + (size_t)(gp * 256 + (idx >> 3)) * 256 + kt * 64 + (idx & 7) * 8, stB + idx * 8);
    }
  };

  // ---- phase 1: h1 = mish(H x W1^T + b1) ----
  STAGE_A(0, 0);
  STAGE_B(W1b, 0);
  __syncthreads();
  int cur = 0;
  for (int kt = 0; kt < 4; ++kt) {
    if (kt < 3) STAGE_A(cur ^ 1, kt + 1);   // A(next) flies under MFMA
    const unsigned short* lA = stA + cur * 4096;
#pragma unroll
    for (int kk = 0; kk < 2; ++kk) {
      bf16x8 af[2], bfr[4];
#pragma unroll
      for (int f2 = 0; f2 < 2; ++f2)
        af[f2] = *reinterpret_cast<const bf16x8*>(lA + (wm * 32 + f2 * 16 + l15) * 64 + (((kk * 4 + l4) ^ sw) << 3));
#pragma unroll
      for (int f4 = 0; f4 < 4; ++f4)
        bfr[f4] = *reinterpret_cast<const bf16x8*>(stB + (wn * 64 + f4 * 16 + l15) * 64 + (((kk * 4 + l4) ^ sw) << 3));
#pragma unroll
      for (int i = 0; i < 2; ++i)
#pragma unroll
        for (int j = 0; j < 4; ++j)
          acc[i][j] = __builtin_amdgcn_mfma_f32_16x16x32_bf16(af[i], bfr[j], acc[i][j], 0, 0, 0);
    }
    __syncthreads();                         // stB readers done; A(next) drained
    if (kt < 3) {
      STAGE_B(W1b, kt + 1);
      __syncthreads();                       // B(next) ready
    }
    cur ^= 1;
  }
  // h1 = mish(acc + b1) -> LDS (swizzled per 64-chunk)
#pragma unroll
  for (int j = 0; j < 4; ++j) {
    const int c = wn * 64 + j * 16 + l15;
    const float bi = b1[gp * 256 + c];
#pragma unroll
    for (int i = 0; i < 2; ++i) {
      const int r0 = wm * 32 + i * 16 + l4 * 4;
#pragma unroll
      for (int e = 0; e < 4; ++e) {
        const int r = r0 + e;
        h1[r * 256 + swoff(c, r)] = f2b(mish_f(acc[i][j][e] + bi));
      }
    }
  }
  __syncthreads();

  // ---- phase 2: o = h1 x W2^T + b2 ----
#pragma unroll
  for (int i = 0; i < 2; ++i)
#pragma unroll
    for (int j = 0; j < 4; ++j) acc[i][j] = zero;
  for (int kt = 0; kt < 4; ++kt) {
    STAGE_B(W2b, kt);
    __syncthreads();                         // W2 tile ready
#pragma unroll
    for (int kk = 0; kk < 2; ++kk) {
      bf16x8 af[2], bfr[4];
#pragma unroll
      for (int f2 = 0; f2 < 2; ++f2)
        af[f2] = *reinterpret_cast<const bf16x8*>(
            h1 + (wm * 32 + f2 * 16 + l15) * 256 + kt * 64 + (((kk * 4 + l4) ^ sw) << 3));
#pragma unroll
      for (int f4 = 0; f4 < 4; ++f4)
        bfr[f4] = *reinterpret_cast<const bf16x8*>(stB + (wn * 64 + f4 * 16 + l15) * 64 + (((kk * 4 + l4) ^ sw) << 3));
#pragma unroll
      for (int i = 0; i < 2; ++i)
#pragma unroll
        for (int j = 0; j < 4; ++j)
          acc[i][j] = __builtin_amdgcn_mfma_f32_16x16x32_bf16(af[i], bfr[j], acc[i][j], 0, 0, 0);
    }
    __syncthreads();                         // stB readers done before restage
  }
  // epilogue: o + b2 -> bf16, LDS transpose (reuse stA/stB region) -> linear dwordx4
  unsigned short* tr = stA;                  // [64][256] = 16384 shorts (fits in stA+stB)
#pragma unroll
  for (int j = 0; j < 4; ++j) {
    const int c = wn * 64 + j * 16 + l15;
    const float bi = b2[gp * 256 + c];
#pragma unroll
    for (int i = 0; i < 2; ++i) {
      const int r0 = wm * 32 + i * 16 + l4 * 4;
#pragma unroll
      for (int e = 0; e < 4; ++e) {
        const int r = r0 + e;
        tr[r * 256 + swoff(c, r)] = f2b(acc[i][j][e] + bi);
      }
    }
  }
  __syncthreads();
  {
    unsigned short* Og = Obuf + (size_t)gp * 1048576;
#pragma unroll
    for (int it = 0; it < 4; ++it) {
      int idx = it * 512 + t;
      int row = idx >> 5, seg = idx & 31;
      int c8 = swoff(seg * 8, row);
      uint4 v = *(const uint4*)(tr + row * 256 + c8);
      *(uint4*)(Og + (size_t)(m0 + row) * 256 + seg * 8) = v;
    }
  }
}

// ---- final: copy = sum_{gp<9} o, jump = sum_{gp>=9} o, out = copy*jump ----
__global__ __launch_bounds__(256) void final_k(const unsigned short* __restrict__ O, float* __restrict__ out) {
  const size_t base = ((size_t)blockIdx.x * 256 + threadIdx.x) * 8;
  float cs[8], js[8];
#pragma unroll
  for (int e = 0; e < 8; ++e) { cs[e] = 0.f; js[e] = 0.f; }
#pragma unroll
  for (int gp = 0; gp < 27; ++gp) {
    uint4 v = *(const uint4*)(O + (size_t)gp * 1048576 + base);
    const unsigned short* pv = (const unsigned short*)&v;
    if (gp < 9) {
#pragma unroll
      for (int e = 0; e < 8; ++e) cs[e] += b2f(pv[e]);
    } else {
#pragma unroll
      for (int e = 0; e < 8; ++e) js[e] += b2f(pv[e]);
    }
  }
  float4 o0 = {cs[0] * js[0], cs[1] * js[1], cs[2] * js[2], cs[3] * js[3]};
  float4 o1 = {cs[4] * js[4], cs[5] * js[5], cs[6] * js[6], cs[7] * js[7]};
  *(float4*)(out + base) = o0;
  *(float4*)(out + base + 4) = o1;
}

extern "C" void kernel_launch(void* const* d_in, const int* in_sizes, int n_in,
                              void* d_out, int out_size, void* d_ws, size_t ws_size,
                              hipStream_t stream) {
  const float* X     = (const float*)d_in[0];
  const float* W5    = (const float*)d_in[1];
  const float* b5    = (const float*)d_in[2];
  const float* gamma = (const float*)d_in[3];
  const float* beta  = (const float*)d_in[4];
  const float* rmean = (const float*)d_in[5];
  const float* rvar  = (const float*)d_in[6];
  const float* W1    = (const float*)d_in[7];
  const float* b1    = (const float*)d_in[8];
  const float* W2    = (const float*)d_in[9];
  const float* b2    = (const float*)d_in[10];
  float* out = (float*)d_out;
  char* ws = (char*)d_ws;

  // ws layout (bytes), all 16B-aligned
  unsigned short* W5c  = (unsigned short*)(ws);              //  7,962,624
  unsigned short* W1b  = (unsigned short*)(ws + 7962624);    //  3,538,944
  unsigned short* W2b  = (unsigned short*)(ws + 11501568);   //  3,538,944
  float*          bn_a = (float*)(ws + 15040512);            //     27,648
  float*          bn_c = (float*)(ws + 15068160);            //     27,648
  unsigned short* Xb   = (unsigned short*)(ws + 15095808);   // 25,690,112
  unsigned short* Hbuf = (unsigned short*)(ws + 40785920);   // 56,623,104
  unsigned short* Obuf = (unsigned short*)(ws + 97409024);   // 56,623,104

  // allow 80 KB dynamic LDS for the fused kernel (host-side, idempotent)
  (void)hipFuncSetAttribute(reinterpret_cast<const void*>(gemm23f_k),
                            hipFuncAttributeMaxDynamicSharedMemorySize, 81920);

  prep_x_k<<<4096, 256, 0, stream>>>(X, Xb);
  prep_w5_k<<<15552, 256, 0, stream>>>(W5, W5c);
  prep_w12_k<<<6912, 256, 0, stream>>>(W1, W2, W1b, W2b);
  prep_bn_k<<<27, 256, 0, stream>>>(b5, gamma, beta, rmean, rvar, bn_a, bn_c);

  gemm1_k<<<dim3(32, 2, 27), 512, 0, stream>>>(Xb, W5c, bn_a, bn_c, Hbuf);
  gemm23f_k<<<dim3(64, 27), 512, 81920, stream>>>(Hbuf, W1b, W2b, b1, b2, Obuf);
  final_k<<<512, 256, 0, stream>>>(Obuf, out);
}